// Round 12
// baseline (4021.078 us; speedup 1.0000x reference)
//
#include <hip/hip_runtime.h>
#include <hip/hip_bf16.h>

typedef __attribute__((ext_vector_type(8)))  short short8;
typedef __attribute__((ext_vector_type(16))) float f32x16;
typedef __attribute__((ext_vector_type(4)))  unsigned int uint4v;

#define TSTEPS 1024
#define BATCH  128
#define NIN    256
#define NHID   512
#define GM     4
#define MBLK   32

#define DSLOT  32768     // bytes per (group,slot) fragment data: 32 kb x 32 row x 2 half x 16B
#define DGRP   65536     // per group (2 slots)
#define TAGOFF 262144    // tag region base in ws
#define TGRP   8192      // per group tags (2 slots x 4096)
#define TSLOT  4096      // 64 tags x 64B

__device__ __forceinline__ unsigned short f2bf(float f) {
  unsigned int u = __builtin_bit_cast(unsigned int, f);
  u += 0x7fffu + ((u >> 16) & 1u);
  return (unsigned short)(u >> 16);
}

__device__ __forceinline__ unsigned long long pack4(float a, float b, float c, float d) {
  return (unsigned long long)f2bf(a)
       | ((unsigned long long)f2bf(b) << 16)
       | ((unsigned long long)f2bf(c) << 32)
       | ((unsigned long long)f2bf(d) << 48);
}

__device__ __forceinline__ float sigf(float x) {
  return 1.0f / (1.0f + __expf(-x));
}
__device__ __forceinline__ float tanh_fast(float x) {
  x = fminf(fmaxf(x, -15.0f), 15.0f);
  float e = __expf(2.0f * x);
  return (e - 1.0f) / (e + 1.0f);
}

// Zero fragment data (256KB) + tags (32KB): slot0 data=0 == h_0, tags=0 == epoch 0.
__global__ void init_ws_kernel(unsigned long long* w) {
  int idx = blockIdx.x * blockDim.x + threadIdx.x;
  for (int i = idx; i < 36864; i += 16384) w[i] = 0ull;
}

// x fp32 -> bf16 in A-FRAGMENT layout: 16B unit at ((t*16+kb)*128 + m)*32 + half*16
__global__ void convert_x_kernel(const float* __restrict__ x, char* __restrict__ xb2) {
  const int NU = TSTEPS * BATCH * 32;   // 16B units
  for (int v = blockIdx.x * blockDim.x + threadIdx.x; v < NU; v += gridDim.x * blockDim.x) {
    int t  = v >> 12;
    int m  = (v >> 5) & 127;
    int c8 = v & 31;
    const float* s = x + (((size_t)t * BATCH + m) << 8) + c8 * 8;
    float4 f0 = *(const float4*)s;
    float4 f1 = *(const float4*)(s + 4);
    unsigned long long lo = pack4(f0.x, f0.y, f0.z, f0.w);
    unsigned long long hi = pack4(f1.x, f1.y, f1.z, f1.w);
    int kb = c8 >> 1, half = c8 & 1;
    char* d = xb2 + ((((size_t)t * 16 + kb) * 128 + m) << 5) + (half << 4);
    uint4v u;
    u.x = (unsigned int)lo; u.y = (unsigned int)(lo >> 32);
    u.z = (unsigned int)hi; u.w = (unsigned int)(hi >> 32);
    *(uint4v*)d = u;
  }
}

#define MF(r, b, acc) \
  __builtin_amdgcn_mfma_f32_32x32x16_bf16(__builtin_bit_cast(short8, r), b, acc, 0, 0, 0)

#define HISSUE(r, kb_) \
  asm volatile("global_load_dwordx4 %0, %1, off sc0 sc1" : "=v"(r) : "v"(hb + (kb_) * 1024))
#define XISSUE(r, kb_) \
  asm volatile("global_load_dwordx4 %0, %1, off" : "=v"(r) : "v"(xb + (kb_) * 4096))
#define VMW(n) asm volatile("s_waitcnt vmcnt(" #n ")" ::: "memory"); \
  __builtin_amdgcn_sched_barrier(0)

#define CONS8(r0,r1,r2,r3,r4,r5,r6,r7, B) \
  a0 = MF(r0, bfrag[(B)+0], a0); a1 = MF(r1, bfrag[(B)+1], a1); \
  a2 = MF(r2, bfrag[(B)+2], a2); a3 = MF(r3, bfrag[(B)+3], a3); \
  a0 = MF(r4, bfrag[(B)+4], a0); a1 = MF(r5, bfrag[(B)+5], a1); \
  a2 = MF(r6, bfrag[(B)+6], a2); a3 = MF(r7, bfrag[(B)+7], a3);

template <int USE_BF>
__global__ __launch_bounds__(256, 1) void lstm_persistent(
    const float* __restrict__ x,      // fp32 x (mode 0)
    const char* __restrict__ xb2,     // bf16 fragment-layout x (mode 1)
    const float* __restrict__ Wih,
    const float* __restrict__ Whh,
    const float* __restrict__ bih,
    const float* __restrict__ bhh,
    float* __restrict__ out,
    char* __restrict__ ws)
{
  const int tid  = threadIdx.x;
  const int lane = tid & 63;
  const int wv   = tid >> 6;
  const int gm   = blockIdx.x & (GM - 1);
  const int gh   = blockIdx.x >> 2;
  const int m0   = gm * MBLK;
  const int hc0  = gh * 32;

  __shared__ float z_lds[2][4][MBLK][36];   // double-buffered z; the ONLY LDS

  // ---------------- W fragments -> registers ----------------
  const int ncol = lane & 31;
  const int h5   = lane >> 5;
  const int gate = ncol >> 3;
  const int wrow = gate * NHID + hc0 + wv * 8 + (ncol & 7);
  const int kg   = h5 * 8;

  short8 bfrag[48];
#pragma unroll
  for (int kb = 0; kb < 48; ++kb) {
    const float* src = (kb < 16)
        ? (Wih + (size_t)wrow * NIN  + (kb * 16 + kg))
        : (Whh + (size_t)wrow * NHID + (kb * 16 + kg - NIN));
    float4 f0 = *(const float4*)src;
    float4 f1 = *(const float4*)(src + 4);
    short8 b;
    b[0] = (short)f2bf(f0.x); b[1] = (short)f2bf(f0.y);
    b[2] = (short)f2bf(f0.z); b[3] = (short)f2bf(f0.w);
    b[4] = (short)f2bf(f1.x); b[5] = (short)f2bf(f1.y);
    b[6] = (short)f2bf(f1.z); b[7] = (short)f2bf(f1.w);
    bfrag[kb] = b;
  }
  const float bias_c = bih[wrow] + bhh[wrow];

  // gate mapping (R6/R9): thread owns (row tid>>3, cols (tid&7)*4..+3)
  const int grow = tid >> 3;
  const int c4   = (tid & 7) * 4;
  float creg[4] = {0.0f, 0.0f, 0.0f, 0.0f};

  char* db = ws + gm * DGRP;
  char* tb = ws + TAGOFF + gm * TGRP;
  const int frago = (lane & 31) * 32 + h5 * 16;   // consumer within-kb fragment offset
  const int mytag = gh * 4 + wv;
  // producer store offset within slot: kb*1024 + row*32 + half*16 + (c4&7)*2
  const int pso = (2 * gh + (c4 >> 4)) * 1024 + grow * 32 + ((c4 >> 3) & 1) * 16 + (c4 & 7) * 2;

  f32x16 a0, a1, a2, a3;

  // zx phase: acc init + 16 x-part MFMAs from fragment register loads
#define ZXPHASE(tt) { \
    a0 = (f32x16)bias_c; a1 = (f32x16)0.0f; a2 = (f32x16)0.0f; a3 = (f32x16)0.0f; \
    if (USE_BF) { \
      const char* xb = xb2 + (((size_t)(tt) * 16 * 128 + m0 + (lane & 31)) << 5) + (h5 << 4); \
      uint4v x0, x1, x2, x3, x4, x5, x6, x7, x8, x9, x10, x11, x12, x13, x14, x15; \
      XISSUE(x0, 0);  XISSUE(x1, 1);  XISSUE(x2, 2);  XISSUE(x3, 3); \
      XISSUE(x4, 4);  XISSUE(x5, 5);  XISSUE(x6, 6);  XISSUE(x7, 7); \
      XISSUE(x8, 8);  XISSUE(x9, 9);  XISSUE(x10, 10); XISSUE(x11, 11); \
      XISSUE(x12, 12); XISSUE(x13, 13); XISSUE(x14, 14); XISSUE(x15, 15); \
      VMW(8); \
      CONS8(x0, x1, x2, x3, x4, x5, x6, x7, 0) \
      VMW(0); \
      CONS8(x8, x9, x10, x11, x12, x13, x14, x15, 8) \
    } else { \
      const float* xr = x + ((size_t)(tt) * BATCH + m0 + (lane & 31)) * NIN + kg; \
      _Pragma("unroll") \
      for (int kb = 0; kb < 16; kb += 4) { \
        float4 f0, f1; uint4v u; \
        unsigned long long lo, hi; \
        f0 = *(const float4*)(xr + (kb + 0) * 16); f1 = *(const float4*)(xr + (kb + 0) * 16 + 4); \
        lo = pack4(f0.x, f0.y, f0.z, f0.w); hi = pack4(f1.x, f1.y, f1.z, f1.w); \
        u.x = (unsigned int)lo; u.y = (unsigned int)(lo >> 32); u.z = (unsigned int)hi; u.w = (unsigned int)(hi >> 32); \
        a0 = MF(u, bfrag[kb + 0], a0); \
        f0 = *(const float4*)(xr + (kb + 1) * 16); f1 = *(const float4*)(xr + (kb + 1) * 16 + 4); \
        lo = pack4(f0.x, f0.y, f0.z, f0.w); hi = pack4(f1.x, f1.y, f1.z, f1.w); \
        u.x = (unsigned int)lo; u.y = (unsigned int)(lo >> 32); u.z = (unsigned int)hi; u.w = (unsigned int)(hi >> 32); \
        a1 = MF(u, bfrag[kb + 1], a1); \
        f0 = *(const float4*)(xr + (kb + 2) * 16); f1 = *(const float4*)(xr + (kb + 2) * 16 + 4); \
        lo = pack4(f0.x, f0.y, f0.z, f0.w); hi = pack4(f1.x, f1.y, f1.z, f1.w); \
        u.x = (unsigned int)lo; u.y = (unsigned int)(lo >> 32); u.z = (unsigned int)hi; u.w = (unsigned int)(hi >> 32); \
        a2 = MF(u, bfrag[kb + 2], a2); \
        f0 = *(const float4*)(xr + (kb + 3) * 16); f1 = *(const float4*)(xr + (kb + 3) * 16 + 4); \
        lo = pack4(f0.x, f0.y, f0.z, f0.w); hi = pack4(f1.x, f1.y, f1.z, f1.w); \
        u.x = (unsigned int)lo; u.y = (unsigned int)(lo >> 32); u.z = (unsigned int)hi; u.w = (unsigned int)(hi >> 32); \
        a3 = MF(u, bfrag[kb + 3], a3); \
      } \
    } }

  // ---------------- prologue: zx_0 ----------------
  ZXPHASE(0)

  for (int t = 0; t < TSTEPS; ++t) {
    // -------- 1. poll 64 per-wave tags (every wave; lane i watches tag i) ----------
    {
      const char* tp = tb + (t & 1) * TSLOT + lane * 64;
      unsigned int tv;
      do {
        asm volatile("global_load_dword %0, %1, off sc0 sc1" : "=v"(tv) : "v"(tp));
        asm volatile("s_waitcnt vmcnt(0)" ::: "memory");
      } while (!__all((int)(tv == (unsigned int)t)));
      __builtin_amdgcn_sched_barrier(0);
    }

    // -------- 2. h A-fragments direct LLC->register, 2-deep pipelined into MFMAs ----
    {
      const char* hb = db + (t & 1) * DSLOT + frago;
      uint4v hA0, hA1, hA2, hA3, hA4, hA5, hA6, hA7;
      uint4v hB0, hB1, hB2, hB3, hB4, hB5, hB6, hB7;
      HISSUE(hA0, 0);  HISSUE(hA1, 1);  HISSUE(hA2, 2);  HISSUE(hA3, 3);
      HISSUE(hA4, 4);  HISSUE(hA5, 5);  HISSUE(hA6, 6);  HISSUE(hA7, 7);
      HISSUE(hB0, 8);  HISSUE(hB1, 9);  HISSUE(hB2, 10); HISSUE(hB3, 11);
      HISSUE(hB4, 12); HISSUE(hB5, 13); HISSUE(hB6, 14); HISSUE(hB7, 15);
      VMW(8);
      CONS8(hA0, hA1, hA2, hA3, hA4, hA5, hA6, hA7, 16)
      HISSUE(hA0, 16); HISSUE(hA1, 17); HISSUE(hA2, 18); HISSUE(hA3, 19);
      HISSUE(hA4, 20); HISSUE(hA5, 21); HISSUE(hA6, 22); HISSUE(hA7, 23);
      VMW(8);
      CONS8(hB0, hB1, hB2, hB3, hB4, hB5, hB6, hB7, 24)
      HISSUE(hB0, 24); HISSUE(hB1, 25); HISSUE(hB2, 26); HISSUE(hB3, 27);
      HISSUE(hB4, 28); HISSUE(hB5, 29); HISSUE(hB6, 30); HISSUE(hB7, 31);
      VMW(8);
      CONS8(hA0, hA1, hA2, hA3, hA4, hA5, hA6, hA7, 32)
      VMW(0);
      CONS8(hB0, hB1, hB2, hB3, hB4, hB5, hB6, hB7, 40)
    }

    // -------- 3. z -> LDS (double-buffered slot t&1), barrier (b) -------------------
    {
      f32x16 acc = (a0 + a1) + (a2 + a3);
#pragma unroll
      for (int r = 0; r < 16; ++r) {
        int zr = (r & 3) + 8 * (r >> 2) + 4 * h5;
        z_lds[t & 1][wv][zr][ncol] = acc[r];
      }
    }
    __syncthreads();                       // (b) — the only barrier per step

    // -------- 4. gates + cell update + publish --------------------------------------
    {
      const int wz = c4 >> 3;
      const int cc = c4 & 7;
      const float* zrow = &z_lds[t & 1][wz][grow][0];
      float4 vi = *(const float4*)&zrow[ 0 + cc];
      float4 vf = *(const float4*)&zrow[ 8 + cc];
      float4 vg = *(const float4*)&zrow[16 + cc];
      float4 vo = *(const float4*)&zrow[24 + cc];
      float zi[4] = {vi.x, vi.y, vi.z, vi.w};
      float zf[4] = {vf.x, vf.y, vf.z, vf.w};
      float zg[4] = {vg.x, vg.y, vg.z, vg.w};
      float zo[4] = {vo.x, vo.y, vo.z, vo.w};
      float hnv[4];
#pragma unroll
      for (int u = 0; u < 4; ++u) {
        float iv = sigf(zi[u]);
        float fv = sigf(zf[u]);
        float gv = tanh_fast(zg[u]);
        float ov = sigf(zo[u]);
        float cn = fv * creg[u] + iv * gv;
        creg[u] = cn;
        hnv[u] = ov * tanh_fast(cn);
      }
      if (t == TSTEPS - 1) {
        size_t o = (size_t)(m0 + grow) * NHID + hc0 + c4;
        float4 hq; hq.x = hnv[0]; hq.y = hnv[1]; hq.z = hnv[2]; hq.w = hnv[3];
        float4 cq; cq.x = creg[0]; cq.y = creg[1]; cq.z = creg[2]; cq.w = creg[3];
        *(float4*)&out[o]          = hq;
        *(float4*)&out[65536 + o]  = hq;
        *(float4*)&out[131072 + o] = cq;
      } else {
        // 8B fragment-layout data store, per-wave drain, per-wave tag
        unsigned long long hp = pack4(hnv[0], hnv[1], hnv[2], hnv[3]);
        char* pd = db + ((t + 1) & 1) * DSLOT + pso;
        asm volatile("global_store_dwordx2 %0, %1, off sc0 sc1"
                     :: "v"(pd), "v"(hp) : "memory");
        asm volatile("s_waitcnt vmcnt(0)" ::: "memory");
        if (lane == 0) {
          unsigned int tg = (unsigned int)(t + 1);
          char* tp = tb + ((t + 1) & 1) * TSLOT + mytag * 64;
          asm volatile("global_store_dword %0, %1, off sc0 sc1"
                       :: "v"(tp), "v"(tg) : "memory");
        }
      }
    }

    // -------- 5. zx_{t+1} (x fragment loads overlap other blocks' phases) -----------
    if (t < TSTEPS - 1) {
      ZXPHASE(t + 1)
    }
  }
#undef ZXPHASE
}

extern "C" void kernel_launch(void* const* d_in, const int* in_sizes, int n_in,
                              void* d_out, int out_size, void* d_ws, size_t ws_size,
                              hipStream_t stream) {
  const float* x   = (const float*)d_in[0];
  const float* Wih = (const float*)d_in[1];
  const float* Whh = (const float*)d_in[2];
  const float* bih = (const float*)d_in[3];
  const float* bhh = (const float*)d_in[4];
  float* out = (float*)d_out;

  char* ws = (char*)d_ws;
  char* xb2 = ws + (1 << 20);   // 64 MB bf16 fragment-layout x

  size_t need = (size_t)(1 << 20) + (size_t)TSTEPS * BATCH * NIN * 2;
  bool bf = ws_size >= need;

  hipLaunchKernelGGL(init_ws_kernel, dim3(64), dim3(256), 0, stream,
                     (unsigned long long*)ws);
  if (bf) {
    hipLaunchKernelGGL(convert_x_kernel, dim3(8192), dim3(256), 0, stream, x, xb2);
    hipLaunchKernelGGL((lstm_persistent<1>), dim3(64), dim3(256), 0, stream,
                       x, xb2, Wih, Whh, bih, bhh, out, ws);
  } else {
    hipLaunchKernelGGL((lstm_persistent<0>), dim3(64), dim3(256), 0, stream,
                       x, xb2, Wih, Whh, bih, bhh, out, ws);
  }
}